// Round 1
// baseline (2603.590 us; speedup 1.0000x reference)
//
#include <hip/hip_runtime.h>
#include <hip/hip_bf16.h>

typedef unsigned short u16;
typedef __attribute__((ext_vector_type(8))) short bf16x8;
typedef __attribute__((ext_vector_type(4))) float f32x4;

#define NIT 4
#define NCLS 21
#define BS 8
#define CIN 2048
#define COUT 1024
#define WH 1024

__device__ __forceinline__ u16 f2bf(float f) {
  union { float f; unsigned u; } v; v.f = f;
  unsigned r = v.u + 0x7fffu + ((v.u >> 16) & 1u);
  return (u16)(r >> 16);
}
__device__ __forceinline__ float bf2f(u16 h) {
  union { unsigned u; float f; } v; v.u = ((unsigned)h) << 16;
  return v.f;
}

#define GLDS16(gp, lp) __builtin_amdgcn_global_load_lds( \
    (const __attribute__((address_space(1))) unsigned int*)(gp), \
    (__attribute__((address_space(3))) unsigned int*)(lp), 16, 0, 0)

// ---------------- prep: conv2d_w [it][co][ci][3][3] f32 -> wt [it][tap][co][ci] bf16
__global__ void prep_w_kernel(const float* __restrict__ w, u16* __restrict__ wt) {
  int it = blockIdx.x >> 10, co = blockIdx.x & 1023;
  const float* src = w + (size_t)(it * 1024 + co) * (CIN * 9);
  __shared__ float ls[2304];
  int t = threadIdx.x;
  for (int chunk = 0; chunk < 8; ++chunk) {
    for (int i = t; i < 2304; i += 256) ls[i] = src[chunk * 2304 + i];
    __syncthreads();
    #pragma unroll
    for (int tap = 0; tap < 9; ++tap) {
      float v = ls[t * 9 + tap];
      wt[(((size_t)(it * 9 + tap) * 1024 + co) * CIN) + chunk * 256 + t] = f2bf(v);
    }
    __syncthreads();
  }
}

// ---------------- prep: x [b][ci][p] f32 -> xT [b][p][ci] bf16 (tiled transpose)
__global__ void prep_x_kernel(const float* __restrict__ x, u16* __restrict__ xT) {
  int bid = blockIdx.x;
  int pT = bid & 15, ciT = (bid >> 4) & 31, b = bid >> 9;
  __shared__ float ls[64][65];
  int t = threadIdx.x;
  int tr = t >> 6, tc = t & 63;
  const float* xp = x + ((size_t)b * CIN + ciT * 64) * WH + pT * 64;
  #pragma unroll
  for (int r = 0; r < 16; ++r) {
    int ci = r * 4 + tr;
    ls[ci][tc] = xp[(size_t)ci * WH + tc];
  }
  __syncthreads();
  u16* xtp = xT + ((size_t)b * WH + pT * 64) * CIN + ciT * 64;
  #pragma unroll
  for (int r = 0; r < 16; ++r) {
    int p = r * 4 + tr;
    xtp[(size_t)p * CIN + tc] = f2bf(ls[tc][p]);
  }
}

// ---------------- norm: diffW [b][m][n] -> normT bf16 (threshold + row-normalize)
__global__ void norm_kernel(const float* __restrict__ diffW, u16* __restrict__ normT) {
  int b = blockIdx.x >> 10, m = blockIdx.x & 1023;
  const float* row = diffW + ((size_t)(b * 1024 + m)) * 1024;
  int t = threadIdx.x;
  float v[4]; float s = 0.f;
  #pragma unroll
  for (int i = 0; i < 4; ++i) {
    float x = row[t + i * 256];
    x = (x > 0.8f) ? x : 0.f;
    v[i] = x; s += x;
  }
  #pragma unroll
  for (int off = 1; off < 64; off <<= 1) s += __shfl_xor(s, off);
  __shared__ float red[4];
  if ((t & 63) == 0) red[t >> 6] = s;
  __syncthreads();
  float inv = 1.f / (red[0] + red[1] + red[2] + red[3]);
  u16* orow = normT + ((size_t)(b * 1024 + m)) * 1024;
  #pragma unroll
  for (int i = 0; i < 4; ++i) orow[t + i * 256] = f2bf(v[i] * inv);
}

__global__ void zero_kernel(float* p) { p[threadIdx.x] = 0.f; }

// ---------------- conv as implicit GEMM: C[co][p] = sum_{tap,ci} Wt[tap][co][ci]*xT[p'][ci]
__global__ __launch_bounds__(256, 2)
void conv_gemm_kernel(const u16* __restrict__ wt, const u16* __restrict__ xT,
                      const float* __restrict__ bias, const u16* __restrict__ zpage,
                      u16* __restrict__ out_all) {
  int bid = blockIdx.x;
  int nt = bid & 7, mt = (bid >> 3) & 7, b = (bid >> 6) & 7, it = bid >> 9;
  int M0 = mt * 128, N0 = nt * 128;
  int tid = threadIdx.x, wave = tid >> 6, lane = tid & 63;
  int wm = (wave >> 1) * 64, wn = (wave & 1) * 64;
  int srow = wave * 8 + (lane >> 3);
  int scol = (lane & 7) * 8;

  __shared__ u16 As[128 * 64];
  __shared__ u16 Bs[128 * 64];

  const int dil = (it == 0) ? 6 : (it == 1) ? 12 : (it == 2) ? 18 : 24;
  const u16* xTb = xT + (size_t)b * WH * CIN;
  const u16* wt_it = wt + (size_t)it * 9 * COUT * CIN;
  const float* bias_it = bias + it * COUT;

  f32x4 acc[4][4] = {};

  size_t aoff[4];
  #pragma unroll
  for (int r = 0; r < 4; ++r) aoff[r] = (size_t)(M0 + r * 32 + srow) * CIN + scol;

  for (int tap = 0; tap < 9; ++tap) {
    int dy = (tap / 3 - 1) * dil, dx = (tap % 3 - 1) * dil;
    const u16* Atap = wt_it + (size_t)tap * COUT * CIN;
    const u16* bptr[4];
    #pragma unroll
    for (int r = 0; r < 4; ++r) {
      int n = N0 + r * 32 + srow;
      int py = (n >> 5) + dy, px = (n & 31) + dx;
      bool valid = ((unsigned)py < 32u) && ((unsigned)px < 32u);
      bptr[r] = valid ? (xTb + (size_t)(py * 32 + px) * CIN + scol) : (const u16*)0;
    }
    for (int k2 = 0; k2 < 32; ++k2) {
      int kc = k2 * 64;
      #pragma unroll
      for (int r = 0; r < 4; ++r) {
        GLDS16(Atap + aoff[r] + kc, &As[(r * 32 + wave * 8) * 64]);
        const u16* gb = bptr[r] ? bptr[r] + kc : zpage;
        GLDS16(gb, &Bs[(r * 32 + wave * 8) * 64]);
      }
      __syncthreads();
      #pragma unroll
      for (int ks = 0; ks < 2; ++ks) {
        bf16x8 af[4], bfr[4];
        #pragma unroll
        for (int mf = 0; mf < 4; ++mf) {
          int row = wm + mf * 16 + (lane & 15);
          af[mf] = *(const bf16x8*)((const char*)As + row * 128 + ks * 64 + (lane >> 4) * 16);
        }
        #pragma unroll
        for (int nf = 0; nf < 4; ++nf) {
          int col = wn + nf * 16 + (lane & 15);
          bfr[nf] = *(const bf16x8*)((const char*)Bs + col * 128 + ks * 64 + (lane >> 4) * 16);
        }
        #pragma unroll
        for (int mf = 0; mf < 4; ++mf)
          #pragma unroll
          for (int nf = 0; nf < 4; ++nf)
            acc[mf][nf] = __builtin_amdgcn_mfma_f32_16x16x32_bf16(af[mf], bfr[nf], acc[mf][nf], 0, 0, 0);
      }
      __syncthreads();
    }
  }

  u16* outp = out_all + (size_t)(it * BS + b) * COUT * WH;
  #pragma unroll
  for (int mf = 0; mf < 4; ++mf)
    #pragma unroll
    for (int nf = 0; nf < 4; ++nf) {
      int col = N0 + wn + nf * 16 + (lane & 15);
      #pragma unroll
      for (int j = 0; j < 4; ++j) {
        int row = M0 + wm + mf * 16 + (lane >> 4) * 4 + j;
        outp[(size_t)row * WH + col] = f2bf(acc[mf][nf][j] + bias_it[row]);
      }
    }
}

// ---------------- od = out @ norm^T  (A=out_all[it][b], B^T=normT[b]) -> od_all bf16
__global__ __launch_bounds__(256, 2)
void od_gemm_kernel(const u16* __restrict__ A_all, const u16* __restrict__ BT_all,
                    u16* __restrict__ C_all) {
  int bid = blockIdx.x;
  int nt = bid & 7, mt = (bid >> 3) & 7, b = (bid >> 6) & 7, it = bid >> 9;
  int M0 = mt * 128, N0 = nt * 128;
  int tid = threadIdx.x, wave = tid >> 6, lane = tid & 63;
  int wm = (wave >> 1) * 64, wn = (wave & 1) * 64;
  int srow = wave * 8 + (lane >> 3);
  int scol = (lane & 7) * 8;

  __shared__ u16 As[128 * 64];
  __shared__ u16 Bs[128 * 64];

  const u16* A = A_all + (size_t)(it * BS + b) * 1024 * 1024;
  const u16* BT = BT_all + (size_t)b * 1024 * 1024;
  u16* C = C_all + (size_t)(it * BS + b) * 1024 * 1024;

  f32x4 acc[4][4] = {};
  for (int kt = 0; kt < 16; ++kt) {
    int kc = kt * 64;
    #pragma unroll
    for (int r = 0; r < 4; ++r) {
      GLDS16(A + (size_t)(M0 + r * 32 + srow) * 1024 + kc + scol, &As[(r * 32 + wave * 8) * 64]);
      GLDS16(BT + (size_t)(N0 + r * 32 + srow) * 1024 + kc + scol, &Bs[(r * 32 + wave * 8) * 64]);
    }
    __syncthreads();
    #pragma unroll
    for (int ks = 0; ks < 2; ++ks) {
      bf16x8 af[4], bfr[4];
      #pragma unroll
      for (int mf = 0; mf < 4; ++mf) {
        int row = wm + mf * 16 + (lane & 15);
        af[mf] = *(const bf16x8*)((const char*)As + row * 128 + ks * 64 + (lane >> 4) * 16);
      }
      #pragma unroll
      for (int nf = 0; nf < 4; ++nf) {
        int col = wn + nf * 16 + (lane & 15);
        bfr[nf] = *(const bf16x8*)((const char*)Bs + col * 128 + ks * 64 + (lane >> 4) * 16);
      }
      #pragma unroll
      for (int mf = 0; mf < 4; ++mf)
        #pragma unroll
        for (int nf = 0; nf < 4; ++nf)
          acc[mf][nf] = __builtin_amdgcn_mfma_f32_16x16x32_bf16(af[mf], bfr[nf], acc[mf][nf], 0, 0, 0);
    }
    __syncthreads();
  }

  #pragma unroll
  for (int mf = 0; mf < 4; ++mf)
    #pragma unroll
    for (int nf = 0; nf < 4; ++nf) {
      int col = N0 + wn + nf * 16 + (lane & 15);
      #pragma unroll
      for (int j = 0; j < 4; ++j) {
        int row = M0 + wm + mf * 16 + (lane >> 4) * 4 + j;
        C[(size_t)row * 1024 + col] = f2bf(acc[mf][nf][j]);
      }
    }
}

// ---------------- 21-class projection: dst[ib][c][n] = sum_d w1[it][c][d]*src[ib][d][n]
__global__ void o2proj_kernel(const u16* __restrict__ src, const float* __restrict__ w1,
                              float* __restrict__ dst) {
  int idx = blockIdx.x * 256 + threadIdx.x;   // 32768 = NIT*BS*1024
  int n = idx & 1023, ib = idx >> 10;
  int it = ib >> 3;
  const u16* sp = src + ((size_t)ib << 20) + n;
  const float* w1p = w1 + it * NCLS * 1024;
  float acc[NCLS];
  #pragma unroll
  for (int c = 0; c < NCLS; ++c) acc[c] = 0.f;
  for (int dd = 0; dd < 1024; ++dd) {
    float v = bf2f(sp[(size_t)dd << 10]);
    #pragma unroll
    for (int c = 0; c < NCLS; ++c) acc[c] += w1p[c * 1024 + dd] * v;
  }
  float* dp = dst + ((size_t)ib * NCLS) * 1024 + n;
  #pragma unroll
  for (int c = 0; c < NCLS; ++c) dp[(size_t)c << 10] = acc[c];
}

// ---------------- wei_cum = softmax_c( sum_it (o2+b1)/4 )  -> d_out section
__global__ void weicum_kernel(const float* __restrict__ o2_all, const float* __restrict__ b1,
                              float* __restrict__ wc_out) {
  int idx = blockIdx.x * 256 + threadIdx.x;   // 8192
  int m = idx & 1023, b = idx >> 10;
  float acc[NCLS];
  #pragma unroll
  for (int c = 0; c < NCLS; ++c) acc[c] = 0.f;
  for (int it = 0; it < NIT; ++it) {
    const float* p = o2_all + ((size_t)(it * BS + b) * NCLS) * 1024 + m;
    #pragma unroll
    for (int c = 0; c < NCLS; ++c) acc[c] += p[(size_t)c << 10];
  }
  float mx = -1e30f;
  #pragma unroll
  for (int c = 0; c < NCLS; ++c) {
    float bsum = 0.f;
    #pragma unroll
    for (int it = 0; it < NIT; ++it) bsum += b1[it * NCLS + c];
    acc[c] = (acc[c] + bsum) * 0.25f;
    mx = fmaxf(mx, acc[c]);
  }
  float s = 0.f;
  #pragma unroll
  for (int c = 0; c < NCLS; ++c) { acc[c] = expf(acc[c] - mx); s += acc[c]; }
  float inv = 1.f / s;
  float* op = wc_out + ((size_t)b * NCLS) * 1024 + m;
  #pragma unroll
  for (int c = 0; c < NCLS; ++c) op[(size_t)c << 10] = acc[c] * inv;
}

// ---------------- inp = softmax_c(wei_cum)
__global__ void inp_kernel(const float* __restrict__ wc, float* __restrict__ inp) {
  int idx = blockIdx.x * 256 + threadIdx.x;   // 8192
  int n = idx & 1023, b = idx >> 10;
  const float* p = wc + ((size_t)b * NCLS) * 1024 + n;
  float v[NCLS]; float mx = -1e30f;
  #pragma unroll
  for (int c = 0; c < NCLS; ++c) { v[c] = p[(size_t)c << 10]; mx = fmaxf(mx, v[c]); }
  float s = 0.f;
  #pragma unroll
  for (int c = 0; c < NCLS; ++c) { v[c] = expf(v[c] - mx); s += v[c]; }
  float inv = 1.f / s;
  float* op = inp + ((size_t)b * NCLS) * 1024 + n;
  #pragma unroll
  for (int c = 0; c < NCLS; ++c) op[(size_t)c << 10] = v[c] * inv;
}

// ---------------- per-(it,b,c): wei = softmax_n(inp*exp(pw)); pred = sum_n wei*proj + b1
__global__ void weipred_kernel(const float* __restrict__ inp, const float* __restrict__ proj,
                               const float* __restrict__ pool_w, const float* __restrict__ b1,
                               float* __restrict__ pred, float* __restrict__ wei_out) {
  int bid = blockIdx.x;                 // it*168 + b*21 + c
  int it = bid / 168, r = bid % 168;
  int b = r / NCLS, c = r % NCLS;
  int t = threadIdx.x;
  float scale = expf(pool_w[it * NCLS + c]);
  const float* ip = inp + ((size_t)(b * NCLS + c)) * 1024;
  float v[4]; float mx = -1e30f;
  #pragma unroll
  for (int i = 0; i < 4; ++i) { v[i] = ip[t + i * 256] * scale; mx = fmaxf(mx, v[i]); }
  __shared__ float red[4];
  #pragma unroll
  for (int off = 1; off < 64; off <<= 1) mx = fmaxf(mx, __shfl_xor(mx, off));
  if ((t & 63) == 0) red[t >> 6] = mx;
  __syncthreads();
  mx = fmaxf(fmaxf(red[0], red[1]), fmaxf(red[2], red[3]));
  __syncthreads();
  float s = 0.f;
  #pragma unroll
  for (int i = 0; i < 4; ++i) { v[i] = expf(v[i] - mx); s += v[i]; }
  #pragma unroll
  for (int off = 1; off < 64; off <<= 1) s += __shfl_xor(s, off);
  if ((t & 63) == 0) red[t >> 6] = s;
  __syncthreads();
  s = red[0] + red[1] + red[2] + red[3];
  float inv = 1.f / s;
  __syncthreads();
  const float* pj = proj + (((size_t)(it * BS + b)) * NCLS + c) * 1024;
  float ps = 0.f;
  #pragma unroll
  for (int i = 0; i < 4; ++i) {
    float wv = v[i] * inv;
    ps += wv * pj[t + i * 256];
    if (it == NIT - 1) wei_out[((size_t)(b * NCLS + c)) * 1024 + t + i * 256] = wv;
  }
  #pragma unroll
  for (int off = 1; off < 64; off <<= 1) ps += __shfl_xor(ps, off);
  if ((t & 63) == 0) red[t >> 6] = ps;
  __syncthreads();
  if (t == 0) pred[bid] = red[0] + red[1] + red[2] + red[3] + b1[it * NCLS + c];
}

// ---------------- prob = sigmoid(mean_it pred)
__global__ void prob_kernel(const float* __restrict__ pred, float* __restrict__ out) {
  int i = threadIdx.x;
  if (i < BS * NCLS) {
    float s = 0.f;
    #pragma unroll
    for (int it = 0; it < NIT; ++it) s += pred[it * BS * NCLS + i];
    s *= 0.25f;
    out[i] = 1.f / (1.f + expf(-s));
  }
}

extern "C" void kernel_launch(void* const* d_in, const int* in_sizes, int n_in,
                              void* d_out, int out_size, void* d_ws, size_t ws_size,
                              hipStream_t stream) {
  const float* x        = (const float*)d_in[0];
  const float* diffW    = (const float*)d_in[1];
  const float* conv2d_w = (const float*)d_in[2];
  const float* conv2d_b = (const float*)d_in[3];
  const float* conv1_w  = (const float*)d_in[4];
  const float* conv1_b  = (const float*)d_in[5];
  const float* pool_w   = (const float*)d_in[6];
  float* out = (float*)d_out;

  char* ws = (char*)d_ws;
  u16*   wt      = (u16*)(ws);                      // 150,994,944 B
  u16*   xT      = (u16*)(ws + 150994944);          //  33,554,432
  u16*   normT   = (u16*)(ws + 184549376);          //  16,777,216
  u16*   out_all = (u16*)(ws + 201326592);          //  67,108,864
  u16*   od_all  = (u16*)(ws + 268435456);          //  67,108,864
  float* o2_all  = (float*)(ws + 335544320);        //   2,752,512
  float* proj    = (float*)(ws + 338296832);        //   2,752,512
  float* inp     = (float*)(ws + 341049344);        //     688,128
  float* pred    = (float*)(ws + 341737472);        //       2,688
  float* zpage   = (float*)(ws + 341740160);        //         256

  float* out_prob = out;                 // 168
  float* out_wc   = out + 168;           // 172032
  float* out_wei  = out + 168 + 172032;  // 172032

  hipLaunchKernelGGL(zero_kernel, dim3(1), dim3(64), 0, stream, zpage);
  hipLaunchKernelGGL(prep_w_kernel, dim3(4096), dim3(256), 0, stream, conv2d_w, wt);
  hipLaunchKernelGGL(prep_x_kernel, dim3(4096), dim3(256), 0, stream, x, xT);
  hipLaunchKernelGGL(norm_kernel, dim3(8192), dim3(256), 0, stream, diffW, normT);
  hipLaunchKernelGGL(conv_gemm_kernel, dim3(2048), dim3(256), 0, stream,
                     wt, xT, conv2d_b, (const u16*)zpage, out_all);
  hipLaunchKernelGGL(od_gemm_kernel, dim3(2048), dim3(256), 0, stream, out_all, normT, od_all);
  hipLaunchKernelGGL(o2proj_kernel, dim3(128), dim3(256), 0, stream, od_all, conv1_w, o2_all);
  hipLaunchKernelGGL(o2proj_kernel, dim3(128), dim3(256), 0, stream, out_all, conv1_w, proj);
  hipLaunchKernelGGL(weicum_kernel, dim3(32), dim3(256), 0, stream, o2_all, conv1_b, out_wc);
  hipLaunchKernelGGL(inp_kernel, dim3(32), dim3(256), 0, stream, out_wc, inp);
  hipLaunchKernelGGL(weipred_kernel, dim3(672), dim3(256), 0, stream,
                     inp, proj, pool_w, conv1_b, pred, out_wei);
  hipLaunchKernelGGL(prob_kernel, dim3(1), dim3(256), 0, stream, pred, out_prob);
}

// Round 2
// 1995.204 us; speedup vs baseline: 1.3049x; 1.3049x over previous
//
#include <hip/hip_runtime.h>
#include <hip/hip_bf16.h>

typedef unsigned short u16;
typedef __attribute__((ext_vector_type(8))) short bf16x8;
typedef __attribute__((ext_vector_type(4))) float f32x4;

#define NIT 4
#define NCLS 21
#define BS 8
#define CIN 2048
#define COUT 1024
#define WH 1024

__device__ __forceinline__ u16 f2bf(float f) {
  union { float f; unsigned u; } v; v.f = f;
  unsigned r = v.u + 0x7fffu + ((v.u >> 16) & 1u);
  return (u16)(r >> 16);
}
__device__ __forceinline__ float bf2f(u16 h) {
  union { unsigned u; float f; } v; v.u = ((unsigned)h) << 16;
  return v.f;
}

#define GLDS16(gp, lp) __builtin_amdgcn_global_load_lds( \
    (const __attribute__((address_space(1))) unsigned int*)(gp), \
    (__attribute__((address_space(3))) unsigned int*)(lp), 16, 0, 0)

// ---------------- prep: conv2d_w [it][co][ci][3][3] f32 -> wt [it][tap][co][ci] bf16
__global__ void prep_w_kernel(const float* __restrict__ w, u16* __restrict__ wt) {
  int it = blockIdx.x >> 10, co = blockIdx.x & 1023;
  const float* src = w + (size_t)(it * 1024 + co) * (CIN * 9);
  __shared__ float ls[2304];
  int t = threadIdx.x;
  for (int chunk = 0; chunk < 8; ++chunk) {
    for (int i = t; i < 2304; i += 256) ls[i] = src[chunk * 2304 + i];
    __syncthreads();
    #pragma unroll
    for (int tap = 0; tap < 9; ++tap) {
      float v = ls[t * 9 + tap];
      wt[(((size_t)(it * 9 + tap) * 1024 + co) * CIN) + chunk * 256 + t] = f2bf(v);
    }
    __syncthreads();
  }
}

// ---------------- prep: x [b][ci][p] f32 -> xT [b][p][ci] bf16 (tiled transpose)
__global__ void prep_x_kernel(const float* __restrict__ x, u16* __restrict__ xT) {
  int bid = blockIdx.x;
  int pT = bid & 15, ciT = (bid >> 4) & 31, b = bid >> 9;
  __shared__ float ls[64][65];
  int t = threadIdx.x;
  int tr = t >> 6, tc = t & 63;
  const float* xp = x + ((size_t)b * CIN + ciT * 64) * WH + pT * 64;
  #pragma unroll
  for (int r = 0; r < 16; ++r) {
    int ci = r * 4 + tr;
    ls[ci][tc] = xp[(size_t)ci * WH + tc];
  }
  __syncthreads();
  u16* xtp = xT + ((size_t)b * WH + pT * 64) * CIN + ciT * 64;
  #pragma unroll
  for (int r = 0; r < 16; ++r) {
    int p = r * 4 + tr;
    xtp[(size_t)p * CIN + tc] = f2bf(ls[tc][p]);
  }
}

// ---------------- norm: diffW [b][m][n] -> normT bf16 (threshold + row-normalize)
__global__ void norm_kernel(const float* __restrict__ diffW, u16* __restrict__ normT) {
  int b = blockIdx.x >> 10, m = blockIdx.x & 1023;
  const float* row = diffW + ((size_t)(b * 1024 + m)) * 1024;
  int t = threadIdx.x;
  float v[4]; float s = 0.f;
  #pragma unroll
  for (int i = 0; i < 4; ++i) {
    float x = row[t + i * 256];
    x = (x > 0.8f) ? x : 0.f;
    v[i] = x; s += x;
  }
  #pragma unroll
  for (int off = 1; off < 64; off <<= 1) s += __shfl_xor(s, off);
  __shared__ float red[4];
  if ((t & 63) == 0) red[t >> 6] = s;
  __syncthreads();
  float inv = 1.f / (red[0] + red[1] + red[2] + red[3]);
  u16* orow = normT + ((size_t)(b * 1024 + m)) * 1024;
  #pragma unroll
  for (int i = 0; i < 4; ++i) orow[t + i * 256] = f2bf(v[i] * inv);
}

__global__ void zero_kernel(float* p) { p[threadIdx.x] = 0.f; }

// ================ 256x256-tile 8-phase GEMM (T2 swizzle + T3/T4 counted vmcnt + T5)
// MODE 0: conv implicit GEMM  C[co][n] = sum_{tap,ci} wt[it][tap][co][ci] * xT[b][n'][ci]
// MODE 1: od GEMM             C[d][m]  = sum_k out[it,b][d][k] * normT[b][m][k]
template<int MODE>
__global__ __launch_bounds__(512, 2)
void gemm8_kernel(const u16* __restrict__ Aall, const u16* __restrict__ Ball,
                  const float* __restrict__ bias, const u16* __restrict__ zpage,
                  u16* __restrict__ Call) {
  const int bid = blockIdx.x;
  const int nt = bid & 3, mt = (bid >> 2) & 3, b = (bid >> 4) & 7, it = bid >> 7;
  const int M0 = mt * 256, N0 = nt * 256;
  const int tid = threadIdx.x, wave = tid >> 6, lane = tid & 63;
  const int wm = wave >> 2, wn = wave & 3;         // 2 x 4 wave grid
  const int NT = (MODE == 0) ? 288 : 16;           // K-tiles of 64

  __shared__ u16 lds[2][2][256][64];               // [buf][A/B][row][col] = 128 KiB

  const u16* Aglob; const u16* Bglob; int dil = 0;
  if (MODE == 0) {
    Aglob = Aall + (size_t)it * 9 * COUT * CIN;
    Bglob = Ball + (size_t)b * WH * CIN;
    dil = 6 * (it + 1);
  } else {
    Aglob = Aall + ((size_t)(it * BS + b) << 20);
    Bglob = Ball + ((size_t)b << 20);
  }

  const int srow = lane >> 3;                  // row within 8-row group
  const int scol16 = (lane & 7) ^ srow;        // inverse-swizzled source col16 (rule #21)

  auto stageA = [&](int jj, int hf, int bb) {
    if (jj >= NT) return;
    #pragma unroll
    for (int i = 0; i < 2; ++i) {
      int row = hf * 128 + i * 64 + wave * 8 + srow;
      const u16* src;
      if (MODE == 0) {
        int tap = jj >> 5;
        src = Aglob + ((size_t)tap * COUT + (M0 + row)) * CIN + ((jj & 31) << 6) + scol16 * 8;
      } else {
        src = Aglob + ((size_t)(M0 + row) << 10) + (jj << 6) + scol16 * 8;
      }
      GLDS16(src, &lds[bb][0][hf * 128 + i * 64 + wave * 8][0]);
    }
  };
  auto stageB = [&](int jj, int hf, int bb) {
    if (jj >= NT) return;
    #pragma unroll
    for (int i = 0; i < 2; ++i) {
      int row = hf * 128 + i * 64 + wave * 8 + srow;
      const u16* src;
      if (MODE == 0) {
        int tap = jj >> 5;
        int n = N0 + row;
        int py = (n >> 5) + (tap / 3 - 1) * dil;
        int px = (n & 31) + (tap % 3 - 1) * dil;
        bool valid = ((unsigned)py < 32u) && ((unsigned)px < 32u);
        src = valid ? (Bglob + (size_t)((py << 5) + px) * CIN + ((jj & 31) << 6) + scol16 * 8)
                    : (zpage + scol16 * 8);
      } else {
        src = Bglob + ((size_t)(N0 + row) << 10) + (jj << 6) + scol16 * 8;
      }
      GLDS16(src, &lds[bb][1][hf * 128 + i * 64 + wave * 8][0]);
    }
  };

  f32x4 acc[8][4] = {};

  const int l15 = lane & 15;
  const int colx[2] = { (((lane >> 4) ^ (lane & 7)) * 16),
                        (((4 + (lane >> 4)) ^ (lane & 7)) * 16) };
  const int arow_byte = (wm * 128 + l15) * 128;
  const int brow_byte = (wn * 64 + l15) * 128;

  // prologue: kt0 fully + B(1) in flight
  stageA(0, 0, 0); stageA(0, 1, 0);
  stageB(0, 0, 0); stageB(0, 1, 0);
  stageB(1, 0, 1); stageB(1, 1, 1);
  asm volatile("s_waitcnt vmcnt(4)" ::: "memory");
  __builtin_amdgcn_s_barrier();
  __builtin_amdgcn_sched_barrier(0);

  bf16x8 bfrag[4][2];
  for (int j = 0; j < NT; ++j) {
    const int p = j & 1;
    const char* Ab = (const char*)&lds[p][0][0][0];
    const char* Bb = (const char*)&lds[p][1][0][0];
    #pragma unroll
    for (int q = 0; q < 4; ++q) {
      // --- ds-read register subtile
      if (q == 0) {
        #pragma unroll
        for (int nf = 0; nf < 4; ++nf) {
          bfrag[nf][0] = *(const bf16x8*)(Bb + brow_byte + nf * 2048 + colx[0]);
          bfrag[nf][1] = *(const bf16x8*)(Bb + brow_byte + nf * 2048 + colx[1]);
        }
      }
      bf16x8 af[2][2];
      #pragma unroll
      for (int m = 0; m < 2; ++m) {
        af[m][0] = *(const bf16x8*)(Ab + arow_byte + (q * 2 + m) * 2048 + colx[0]);
        af[m][1] = *(const bf16x8*)(Ab + arow_byte + (q * 2 + m) * 2048 + colx[1]);
      }
      // --- stage one half-tile (counted pipeline, depth ~1.5 K-tiles)
      if (q == 0) stageA(j + 1, 0, p ^ 1);
      else if (q == 1) stageA(j + 1, 1, p ^ 1);
      else if (q == 2) stageB(j + 2, 0, p);
      else stageB(j + 2, 1, p);

      __builtin_amdgcn_s_barrier();
      asm volatile("s_waitcnt lgkmcnt(0)" ::: "memory");
      __builtin_amdgcn_sched_barrier(0);
      __builtin_amdgcn_s_setprio(1);
      #pragma unroll
      for (int m = 0; m < 2; ++m)
        #pragma unroll
        for (int nf = 0; nf < 4; ++nf) {
          acc[q * 2 + m][nf] = __builtin_amdgcn_mfma_f32_16x16x32_bf16(af[m][0], bfrag[nf][0], acc[q * 2 + m][nf], 0, 0, 0);
          acc[q * 2 + m][nf] = __builtin_amdgcn_mfma_f32_16x16x32_bf16(af[m][1], bfrag[nf][1], acc[q * 2 + m][nf], 0, 0, 0);
        }
      __builtin_amdgcn_s_setprio(0);
      if (q == 3) {
        if (j < NT - 2) { asm volatile("s_waitcnt vmcnt(4)" ::: "memory"); }
        else           { asm volatile("s_waitcnt vmcnt(0)" ::: "memory"); }
      }
      __builtin_amdgcn_s_barrier();
      __builtin_amdgcn_sched_barrier(0);
    }
  }

  // epilogue
  u16* outp = Call + (size_t)(it * BS + b) * COUT * WH;
  const float* bias_it = (MODE == 0) ? (bias + it * COUT) : nullptr;
  #pragma unroll
  for (int mf = 0; mf < 8; ++mf)
    #pragma unroll
    for (int nf = 0; nf < 4; ++nf) {
      int col = N0 + wn * 64 + nf * 16 + l15;
      #pragma unroll
      for (int r = 0; r < 4; ++r) {
        int row = M0 + wm * 128 + mf * 16 + (lane >> 4) * 4 + r;
        float v = acc[mf][nf][r];
        if (MODE == 0) v += bias_it[row];
        outp[((size_t)row << 10) + col] = f2bf(v);
      }
    }
}

// ---------------- 21-class projection: dst[ib][c][n] = sum_d w1[it][c][d]*src[ib][d][n]
__global__ void o2proj_kernel(const u16* __restrict__ src, const float* __restrict__ w1,
                              float* __restrict__ dst) {
  int idx = blockIdx.x * 256 + threadIdx.x;   // 32768 = NIT*BS*1024
  int n = idx & 1023, ib = idx >> 10;
  int it = ib >> 3;
  const u16* sp = src + ((size_t)ib << 20) + n;
  const float* w1p = w1 + it * NCLS * 1024;
  float acc[NCLS];
  #pragma unroll
  for (int c = 0; c < NCLS; ++c) acc[c] = 0.f;
  for (int dd = 0; dd < 1024; ++dd) {
    float v = bf2f(sp[(size_t)dd << 10]);
    #pragma unroll
    for (int c = 0; c < NCLS; ++c) acc[c] += w1p[c * 1024 + dd] * v;
  }
  float* dp = dst + ((size_t)ib * NCLS) * 1024 + n;
  #pragma unroll
  for (int c = 0; c < NCLS; ++c) dp[(size_t)c << 10] = acc[c];
}

// ---------------- wei_cum = softmax_c( sum_it (o2+b1)/4 )
__global__ void weicum_kernel(const float* __restrict__ o2_all, const float* __restrict__ b1,
                              float* __restrict__ wc_out) {
  int idx = blockIdx.x * 256 + threadIdx.x;   // 8192
  int m = idx & 1023, b = idx >> 10;
  float acc[NCLS];
  #pragma unroll
  for (int c = 0; c < NCLS; ++c) acc[c] = 0.f;
  for (int it = 0; it < NIT; ++it) {
    const float* p = o2_all + ((size_t)(it * BS + b) * NCLS) * 1024 + m;
    #pragma unroll
    for (int c = 0; c < NCLS; ++c) acc[c] += p[(size_t)c << 10];
  }
  float mx = -1e30f;
  #pragma unroll
  for (int c = 0; c < NCLS; ++c) {
    float bsum = 0.f;
    #pragma unroll
    for (int it = 0; it < NIT; ++it) bsum += b1[it * NCLS + c];
    acc[c] = (acc[c] + bsum) * 0.25f;
    mx = fmaxf(mx, acc[c]);
  }
  float s = 0.f;
  #pragma unroll
  for (int c = 0; c < NCLS; ++c) { acc[c] = expf(acc[c] - mx); s += acc[c]; }
  float inv = 1.f / s;
  float* op = wc_out + ((size_t)b * NCLS) * 1024 + m;
  #pragma unroll
  for (int c = 0; c < NCLS; ++c) op[(size_t)c << 10] = acc[c] * inv;
}

// ---------------- inp = softmax_c(wei_cum)
__global__ void inp_kernel(const float* __restrict__ wc, float* __restrict__ inp) {
  int idx = blockIdx.x * 256 + threadIdx.x;   // 8192
  int n = idx & 1023, b = idx >> 10;
  const float* p = wc + ((size_t)b * NCLS) * 1024 + n;
  float v[NCLS]; float mx = -1e30f;
  #pragma unroll
  for (int c = 0; c < NCLS; ++c) { v[c] = p[(size_t)c << 10]; mx = fmaxf(mx, v[c]); }
  float s = 0.f;
  #pragma unroll
  for (int c = 0; c < NCLS; ++c) { v[c] = expf(v[c] - mx); s += v[c]; }
  float inv = 1.f / s;
  float* op = inp + ((size_t)b * NCLS) * 1024 + n;
  #pragma unroll
  for (int c = 0; c < NCLS; ++c) op[(size_t)c << 10] = v[c] * inv;
}

// ---------------- per-(it,b,c): wei = softmax_n(inp*exp(pw)); pred = sum_n wei*proj + b1
__global__ void weipred_kernel(const float* __restrict__ inp, const float* __restrict__ proj,
                               const float* __restrict__ pool_w, const float* __restrict__ b1,
                               float* __restrict__ pred, float* __restrict__ wei_out) {
  int bid = blockIdx.x;                 // it*168 + b*21 + c
  int it = bid / 168, r = bid % 168;
  int b = r / NCLS, c = r % NCLS;
  int t = threadIdx.x;
  float scale = expf(pool_w[it * NCLS + c]);
  const float* ip = inp + ((size_t)(b * NCLS + c)) * 1024;
  float v[4]; float mx = -1e30f;
  #pragma unroll
  for (int i = 0; i < 4; ++i) { v[i] = ip[t + i * 256] * scale; mx = fmaxf(mx, v[i]); }
  __shared__ float red[4];
  #pragma unroll
  for (int off = 1; off < 64; off <<= 1) mx = fmaxf(mx, __shfl_xor(mx, off));
  if ((t & 63) == 0) red[t >> 6] = mx;
  __syncthreads();
  mx = fmaxf(fmaxf(red[0], red[1]), fmaxf(red[2], red[3]));
  __syncthreads();
  float s = 0.f;
  #pragma unroll
  for (int i = 0; i < 4; ++i) { v[i] = expf(v[i] - mx); s += v[i]; }
  #pragma unroll
  for (int off = 1; off < 64; off <<= 1) s += __shfl_xor(s, off);
  if ((t & 63) == 0) red[t >> 6] = s;
  __syncthreads();
  s = red[0] + red[1] + red[2] + red[3];
  float inv = 1.f / s;
  __syncthreads();
  const float* pj = proj + (((size_t)(it * BS + b)) * NCLS + c) * 1024;
  float ps = 0.f;
  #pragma unroll
  for (int i = 0; i < 4; ++i) {
    float wv = v[i] * inv;
    ps += wv * pj[t + i * 256];
    if (it == NIT - 1) wei_out[((size_t)(b * NCLS + c)) * 1024 + t + i * 256] = wv;
  }
  #pragma unroll
  for (int off = 1; off < 64; off <<= 1) ps += __shfl_xor(ps, off);
  if ((t & 63) == 0) red[t >> 6] = ps;
  __syncthreads();
  if (t == 0) pred[bid] = red[0] + red[1] + red[2] + red[3] + b1[it * NCLS + c];
}

// ---------------- prob = sigmoid(mean_it pred)
__global__ void prob_kernel(const float* __restrict__ pred, float* __restrict__ out) {
  int i = threadIdx.x;
  if (i < BS * NCLS) {
    float s = 0.f;
    #pragma unroll
    for (int it = 0; it < NIT; ++it) s += pred[it * BS * NCLS + i];
    s *= 0.25f;
    out[i] = 1.f / (1.f + expf(-s));
  }
}

extern "C" void kernel_launch(void* const* d_in, const int* in_sizes, int n_in,
                              void* d_out, int out_size, void* d_ws, size_t ws_size,
                              hipStream_t stream) {
  const float* x        = (const float*)d_in[0];
  const float* diffW    = (const float*)d_in[1];
  const float* conv2d_w = (const float*)d_in[2];
  const float* conv2d_b = (const float*)d_in[3];
  const float* conv1_w  = (const float*)d_in[4];
  const float* conv1_b  = (const float*)d_in[5];
  const float* pool_w   = (const float*)d_in[6];
  float* out = (float*)d_out;

  char* ws = (char*)d_ws;
  u16*   wt      = (u16*)(ws);                      // 150,994,944 B
  u16*   xT      = (u16*)(ws + 150994944);          //  33,554,432
  u16*   normT   = (u16*)(ws + 184549376);          //  16,777,216
  u16*   out_all = (u16*)(ws + 201326592);          //  67,108,864
  u16*   od_all  = (u16*)(ws + 268435456);          //  67,108,864
  float* o2_all  = (float*)(ws + 335544320);        //   2,752,512
  float* proj    = (float*)(ws + 338296832);        //   2,752,512
  float* inp     = (float*)(ws + 341049344);        //     688,128
  float* pred    = (float*)(ws + 341737472);        //       2,688
  float* zpage   = (float*)(ws + 341740160);        //         256

  float* out_prob = out;                 // 168
  float* out_wc   = out + 168;           // 172032
  float* out_wei  = out + 168 + 172032;  // 172032

  hipLaunchKernelGGL(zero_kernel, dim3(1), dim3(64), 0, stream, zpage);
  hipLaunchKernelGGL(prep_w_kernel, dim3(4096), dim3(256), 0, stream, conv2d_w, wt);
  hipLaunchKernelGGL(prep_x_kernel, dim3(4096), dim3(256), 0, stream, x, xT);
  hipLaunchKernelGGL(norm_kernel, dim3(8192), dim3(256), 0, stream, diffW, normT);
  hipLaunchKernelGGL((gemm8_kernel<0>), dim3(512), dim3(512), 0, stream,
                     wt, xT, conv2d_b, (const u16*)zpage, out_all);
  hipLaunchKernelGGL((gemm8_kernel<1>), dim3(512), dim3(512), 0, stream,
                     out_all, normT, conv2d_b, (const u16*)zpage, od_all);
  hipLaunchKernelGGL(o2proj_kernel, dim3(128), dim3(256), 0, stream, od_all, conv1_w, o2_all);
  hipLaunchKernelGGL(o2proj_kernel, dim3(128), dim3(256), 0, stream, out_all, conv1_w, proj);
  hipLaunchKernelGGL(weicum_kernel, dim3(32), dim3(256), 0, stream, o2_all, conv1_b, out_wc);
  hipLaunchKernelGGL(inp_kernel, dim3(32), dim3(256), 0, stream, out_wc, inp);
  hipLaunchKernelGGL(weipred_kernel, dim3(672), dim3(256), 0, stream,
                     inp, proj, pool_w, conv1_b, pred, out_wei);
  hipLaunchKernelGGL(prob_kernel, dim3(1), dim3(256), 0, stream, pred, out_prob);
}

// Round 3
// 1269.279 us; speedup vs baseline: 2.0512x; 1.5719x over previous
//
#include <hip/hip_runtime.h>
#include <hip/hip_bf16.h>

typedef unsigned short u16;
typedef __attribute__((ext_vector_type(8))) short bf16x8;
typedef __attribute__((ext_vector_type(4))) float f32x4;

#define NIT 4
#define NCLS 21
#define BS 8
#define CIN 2048
#define COUT 1024
#define WH 1024

__device__ __forceinline__ u16 f2bf(float f) {
  union { float f; unsigned u; } v; v.f = f;
  unsigned r = v.u + 0x7fffu + ((v.u >> 16) & 1u);
  return (u16)(r >> 16);
}
__device__ __forceinline__ float bf2f(u16 h) {
  union { unsigned u; float f; } v; v.u = ((unsigned)h) << 16;
  return v.f;
}

#define GLDS16(gp, lp) __builtin_amdgcn_global_load_lds( \
    (const __attribute__((address_space(1))) unsigned int*)(gp), \
    (__attribute__((address_space(3))) unsigned int*)(lp), 16, 0, 0)

// ---------------- prep: conv2d_w [it][co][ci][3][3] f32 -> wt [it][tap][co][ci] bf16
__global__ void prep_w_kernel(const float* __restrict__ w, u16* __restrict__ wt) {
  int it = blockIdx.x >> 10, co = blockIdx.x & 1023;
  const float* src = w + (size_t)(it * 1024 + co) * (CIN * 9);
  __shared__ float ls[2304];
  int t = threadIdx.x;
  for (int chunk = 0; chunk < 8; ++chunk) {
    for (int i = t; i < 2304; i += 256) ls[i] = src[chunk * 2304 + i];
    __syncthreads();
    #pragma unroll
    for (int tap = 0; tap < 9; ++tap) {
      float v = ls[t * 9 + tap];
      wt[(((size_t)(it * 9 + tap) * 1024 + co) * CIN) + chunk * 256 + t] = f2bf(v);
    }
    __syncthreads();
  }
}

// ---------------- prep: x [b][ci][p] f32 -> xT [b][p][ci] bf16 (tiled transpose)
__global__ void prep_x_kernel(const float* __restrict__ x, u16* __restrict__ xT) {
  int bid = blockIdx.x;
  int pT = bid & 15, ciT = (bid >> 4) & 31, b = bid >> 9;
  __shared__ float ls[64][65];
  int t = threadIdx.x;
  int tr = t >> 6, tc = t & 63;
  const float* xp = x + ((size_t)b * CIN + ciT * 64) * WH + pT * 64;
  #pragma unroll
  for (int r = 0; r < 16; ++r) {
    int ci = r * 4 + tr;
    ls[ci][tc] = xp[(size_t)ci * WH + tc];
  }
  __syncthreads();
  u16* xtp = xT + ((size_t)b * WH + pT * 64) * CIN + ciT * 64;
  #pragma unroll
  for (int r = 0; r < 16; ++r) {
    int p = r * 4 + tr;
    xtp[(size_t)p * CIN + tc] = f2bf(ls[tc][p]);
  }
}

// ---------------- norm: diffW [b][m][n] -> normT[m][n] bf16 (threshold + row-normalize)
__global__ void norm_kernel(const float* __restrict__ diffW, u16* __restrict__ normT) {
  int b = blockIdx.x >> 10, m = blockIdx.x & 1023;
  const float* row = diffW + ((size_t)(b * 1024 + m)) * 1024;
  int t = threadIdx.x;
  float v[4]; float s = 0.f;
  #pragma unroll
  for (int i = 0; i < 4; ++i) {
    float x = row[t + i * 256];
    x = (x > 0.8f) ? x : 0.f;
    v[i] = x; s += x;
  }
  #pragma unroll
  for (int off = 1; off < 64; off <<= 1) s += __shfl_xor(s, off);
  __shared__ float red[4];
  if ((t & 63) == 0) red[t >> 6] = s;
  __syncthreads();
  float inv = 1.f / (red[0] + red[1] + red[2] + red[3]);
  u16* orow = normT + ((size_t)(b * 1024 + m)) * 1024;
  #pragma unroll
  for (int i = 0; i < 4; ++i) orow[t + i * 256] = f2bf(v[i] * inv);
}

__global__ void zero_kernel(float* p) { p[threadIdx.x] = 0.f; }

// ================ conv implicit GEMM, 256^2 tile, 8-phase (T2+T3+T4+T5)
// C[co][n] = sum_{tap,ci} wt[it][tap][co][ci] * xT[b][n'][ci]
__global__ __launch_bounds__(512, 2)
void conv8_kernel(const u16* __restrict__ wt, const u16* __restrict__ xT,
                  const float* __restrict__ bias, const u16* __restrict__ zpage,
                  u16* __restrict__ out_all) {
  const int bid = blockIdx.x;
  const int nt = bid & 3, mt = (bid >> 2) & 3, b = (bid >> 4) & 7, it = bid >> 7;
  const int M0 = mt * 256, N0 = nt * 256;
  const int tid = threadIdx.x, wave = tid >> 6, lane = tid & 63;
  const int wm = wave >> 2, wn = wave & 3;         // 2 x 4 wave grid
  const int NT = 288;                              // 9 taps x 32 K-tiles of 64

  __shared__ u16 lds[2][2][256][64];               // [buf][A/B][row][col] = 128 KiB

  const int dil = 6 * (it + 1);
  const u16* Aglob = wt + (size_t)it * 9 * COUT * CIN;
  const u16* Bglob = xT + (size_t)b * WH * CIN;

  const int srow = lane >> 3;                  // row within 8-row group
  const int scol16 = (lane & 7) ^ srow;        // inverse-swizzled source col16 (rule #21)

  // precomputed per-lane row base pointers + 36-bit validity mask
  const u16* abase[4]; const u16* bbase[4];
  unsigned long long vmask = 0ull;
  #pragma unroll
  for (int r = 0; r < 4; ++r) {
    int arow = M0 + r * 64 + wave * 8 + srow;
    abase[r] = Aglob + (size_t)arow * CIN + scol16 * 8;
    int n = N0 + r * 64 + wave * 8 + srow;
    bbase[r] = Bglob + (size_t)n * CIN + scol16 * 8;
    int py0 = n >> 5, px0 = n & 31;
    #pragma unroll
    for (int tap = 0; tap < 9; ++tap) {
      int t3 = (tap * 11) >> 5;
      int py = py0 + (t3 - 1) * dil;
      int px = px0 + (tap - t3 * 3 - 1) * dil;
      if (((unsigned)py < 32u) && ((unsigned)px < 32u))
        vmask |= (1ull << (r * 9 + tap));
    }
  }
  const u16* zp = zpage + scol16 * 8;

  auto stageA = [&](int jj, int hf, int bb) {
    if (jj >= NT) return;
    int tap = jj >> 5;
    size_t uoff = (size_t)tap * (COUT * CIN) + (size_t)((jj & 31) << 6);
    #pragma unroll
    for (int i = 0; i < 2; ++i) {
      int r = hf * 2 + i;
      GLDS16(abase[r] + uoff, &lds[bb][0][hf * 128 + i * 64 + wave * 8][0]);
    }
  };
  auto stageB = [&](int jj, int hf, int bb) {
    if (jj >= NT) return;
    int tap = jj >> 5;
    int t3 = (tap * 11) >> 5;
    ptrdiff_t toff = (ptrdiff_t)(((t3 - 1) * 32 + (tap - t3 * 3 - 1)) * dil) * CIN
                   + (ptrdiff_t)((jj & 31) << 6);
    #pragma unroll
    for (int i = 0; i < 2; ++i) {
      int r = hf * 2 + i;
      bool valid = (vmask >> (r * 9 + tap)) & 1ull;
      const u16* src = valid ? (bbase[r] + toff) : zp;
      GLDS16(src, &lds[bb][1][hf * 128 + i * 64 + wave * 8][0]);
    }
  };

  f32x4 acc[8][4] = {};

  const int l15 = lane & 15;
  const int colx[2] = { (((lane >> 4) ^ (lane & 7)) * 16),
                        (((4 + (lane >> 4)) ^ (lane & 7)) * 16) };
  const int arow_byte = (wm * 128 + l15) * 128;
  const int brow_byte = (wn * 64 + l15) * 128;

  // prologue: kt0 fully + B(1) in flight
  stageA(0, 0, 0); stageA(0, 1, 0);
  stageB(0, 0, 0); stageB(0, 1, 0);
  stageB(1, 0, 1); stageB(1, 1, 1);
  asm volatile("s_waitcnt vmcnt(4)" ::: "memory");
  __builtin_amdgcn_s_barrier();
  __builtin_amdgcn_sched_barrier(0);

  bf16x8 bfrag[4][2];
  for (int j = 0; j < NT; ++j) {
    const int p = j & 1;
    const char* Ab = (const char*)&lds[p][0][0][0];
    const char* Bb = (const char*)&lds[p][1][0][0];
    #pragma unroll
    for (int q = 0; q < 4; ++q) {
      // --- ds-read register subtile
      if (q == 0) {
        #pragma unroll
        for (int nf = 0; nf < 4; ++nf) {
          bfrag[nf][0] = *(const bf16x8*)(Bb + brow_byte + nf * 2048 + colx[0]);
          bfrag[nf][1] = *(const bf16x8*)(Bb + brow_byte + nf * 2048 + colx[1]);
        }
      }
      bf16x8 af[2][2];
      #pragma unroll
      for (int m = 0; m < 2; ++m) {
        af[m][0] = *(const bf16x8*)(Ab + arow_byte + (q * 2 + m) * 2048 + colx[0]);
        af[m][1] = *(const bf16x8*)(Ab + arow_byte + (q * 2 + m) * 2048 + colx[1]);
      }
      // --- stage one half-tile (counted pipeline)
      if (q == 0) stageA(j + 1, 0, p ^ 1);
      else if (q == 1) stageA(j + 1, 1, p ^ 1);
      else if (q == 2) stageB(j + 2, 0, p);
      else stageB(j + 2, 1, p);

      __builtin_amdgcn_s_barrier();
      asm volatile("s_waitcnt lgkmcnt(0)" ::: "memory");
      __builtin_amdgcn_sched_barrier(0);
      __builtin_amdgcn_s_setprio(1);
      #pragma unroll
      for (int m = 0; m < 2; ++m)
        #pragma unroll
        for (int nf = 0; nf < 4; ++nf) {
          acc[q * 2 + m][nf] = __builtin_amdgcn_mfma_f32_16x16x32_bf16(af[m][0], bfrag[nf][0], acc[q * 2 + m][nf], 0, 0, 0);
          acc[q * 2 + m][nf] = __builtin_amdgcn_mfma_f32_16x16x32_bf16(af[m][1], bfrag[nf][1], acc[q * 2 + m][nf], 0, 0, 0);
        }
      __builtin_amdgcn_s_setprio(0);
      if (q == 3) {
        if (j < NT - 2) { asm volatile("s_waitcnt vmcnt(4)" ::: "memory"); }
        else           { asm volatile("s_waitcnt vmcnt(0)" ::: "memory"); }
      }
      __builtin_amdgcn_s_barrier();
      __builtin_amdgcn_sched_barrier(0);
    }
  }

  // epilogue
  u16* outp = out_all + (size_t)(it * BS + b) * COUT * WH;
  const float* bias_it = bias + it * COUT;
  #pragma unroll
  for (int mf = 0; mf < 8; ++mf)
    #pragma unroll
    for (int nf = 0; nf < 4; ++nf) {
      int col = N0 + wn * 64 + nf * 16 + l15;
      #pragma unroll
      for (int r = 0; r < 4; ++r) {
        int row = M0 + wm * 128 + mf * 16 + (lane >> 4) * 4 + r;
        outp[((size_t)row << 10) + col] = f2bf(acc[mf][nf][r] + bias_it[row]);
      }
    }
}

// ---------------- P[it,b,c,k] = sum_d w1[it,c,d] * out[it,b,d,k]   (f32 out)
// grid: 128 = slice(32) x kchunk(4); 1024 threads; wave w covers c-group (w&3), k-range ((w>>2)*64)
__global__ __launch_bounds__(1024, 4)
void p_kernel(const u16* __restrict__ out_all, const float* __restrict__ w1,
              float* __restrict__ P) {
  int bidx = blockIdx.x;
  int kch = bidx & 3, sl = bidx >> 2;   // sl = it*8+b
  int it = sl >> 3;
  int t = threadIdx.x;
  int wave = t >> 6, lane = t & 63;
  int g = wave & 3;
  int k = kch * 256 + (wave >> 2) * 64 + lane;
  __shared__ float w1f[21][512];
  const u16* op = out_all + ((size_t)sl << 20) + k;
  const float* w1p = w1 + (size_t)it * NCLS * 1024;
  float acc[6] = {0.f, 0.f, 0.f, 0.f, 0.f, 0.f};
  const int cbase = g * 6;
  for (int h = 0; h < 2; ++h) {
    __syncthreads();
    for (int l = t; l < 21 * 128; l += 1024) {
      int c = l >> 7, qq = l & 127;
      *(f32x4*)&w1f[c][qq * 4] = *(const f32x4*)(w1p + (size_t)c * 1024 + h * 512 + qq * 4);
    }
    __syncthreads();
    const u16* oph = op + ((size_t)(h * 512) << 10);
    #pragma unroll 4
    for (int dq = 0; dq < 128; ++dq) {
      float vv[4];
      #pragma unroll
      for (int j = 0; j < 4; ++j) vv[j] = bf2f(oph[(size_t)(dq * 4 + j) << 10]);
      #pragma unroll
      for (int cj = 0; cj < 6; ++cj) {
        int c = cbase + cj; if (c > 20) c = 20;
        f32x4 w4 = *(const f32x4*)&w1f[c][dq * 4];
        acc[cj] = fmaf(w4[0], vv[0], acc[cj]);
        acc[cj] = fmaf(w4[1], vv[1], acc[cj]);
        acc[cj] = fmaf(w4[2], vv[2], acc[cj]);
        acc[cj] = fmaf(w4[3], vv[3], acc[cj]);
      }
    }
  }
  float* Pp = P + (((size_t)sl * NCLS) << 10) + k;
  #pragma unroll
  for (int cj = 0; cj < 6; ++cj) {
    int c = cbase + cj;
    if (c < NCLS) Pp[(size_t)c << 10] = acc[cj];
  }
}

// ---------------- weicum2: o2sum[c,m] = sum_k Psum[c,k]*normT[m,k]; wc=softmax_c; inp=softmax_c(wc)
__global__ __launch_bounds__(256, 2)
void weicum2_kernel(const float* __restrict__ P, const u16* __restrict__ normT,
                    const float* __restrict__ b1, float* __restrict__ wc_out,
                    float* __restrict__ inp) {
  int bidx = blockIdx.x;  // 32 = b(8)*mch(4)
  int mch = bidx & 3, b = bidx >> 2;
  int t = threadIdx.x;
  __shared__ u16 ps[21][1024];   // Psum as bf16
  for (int l = t; l < 21 * 128; l += 256) {
    int c = l >> 7, qq = l & 127;
    float s[8] = {};
    #pragma unroll
    for (int itp = 0; itp < 4; ++itp) {
      const float* pp = P + ((((size_t)(itp * 8 + b)) * NCLS + c) << 10) + qq * 8;
      f32x4 a0 = *(const f32x4*)pp;
      f32x4 a1 = *(const f32x4*)(pp + 4);
      s[0] += a0[0]; s[1] += a0[1]; s[2] += a0[2]; s[3] += a0[3];
      s[4] += a1[0]; s[5] += a1[1]; s[6] += a1[2]; s[7] += a1[3];
    }
    bf16x8 pv;
    #pragma unroll
    for (int j = 0; j < 8; ++j) pv[j] = (short)f2bf(s[j]);
    *(bf16x8*)&ps[c][qq * 8] = pv;
  }
  __syncthreads();
  int m = mch * 256 + t;
  const u16* nr = normT + ((size_t)(b * 1024 + m)) * 1024;
  float acc[NCLS];
  #pragma unroll
  for (int c = 0; c < NCLS; ++c) acc[c] = 0.f;
  for (int oct = 0; oct < 128; ++oct) {
    bf16x8 nv = *(const bf16x8*)(nr + oct * 8);
    float nf[8];
    #pragma unroll
    for (int j = 0; j < 8; ++j) nf[j] = bf2f((u16)nv[j]);
    #pragma unroll
    for (int c = 0; c < NCLS; ++c) {
      bf16x8 pv = *(const bf16x8*)&ps[c][oct * 8];
      #pragma unroll
      for (int j = 0; j < 8; ++j) acc[c] = fmaf(nf[j], bf2f((u16)pv[j]), acc[c]);
    }
  }
  float mx = -1e30f;
  #pragma unroll
  for (int c = 0; c < NCLS; ++c) {
    float bs = 0.f;
    #pragma unroll
    for (int itp = 0; itp < NIT; ++itp) bs += b1[itp * NCLS + c];
    acc[c] = (acc[c] + bs) * 0.25f;
    mx = fmaxf(mx, acc[c]);
  }
  float s = 0.f;
  #pragma unroll
  for (int c = 0; c < NCLS; ++c) { acc[c] = expf(acc[c] - mx); s += acc[c]; }
  float inv = 1.f / s;
  float* wp = wc_out + (((size_t)b * NCLS) << 10) + m;
  float mx2 = -1e30f;
  #pragma unroll
  for (int c = 0; c < NCLS; ++c) {
    acc[c] *= inv;
    wp[(size_t)c << 10] = acc[c];
    mx2 = fmaxf(mx2, acc[c]);
  }
  float s2 = 0.f;
  #pragma unroll
  for (int c = 0; c < NCLS; ++c) { acc[c] = expf(acc[c] - mx2); s2 += acc[c]; }
  float inv2 = 1.f / s2;
  float* ip = inp + (((size_t)b * NCLS) << 10) + m;
  #pragma unroll
  for (int c = 0; c < NCLS; ++c) ip[(size_t)c << 10] = acc[c] * inv2;
}

// ---------------- per-(it,b,c): wei = softmax_n(inp*exp(pw)); pred = sum_n wei*P + b1
__global__ void weipred_kernel(const float* __restrict__ inp, const float* __restrict__ proj,
                               const float* __restrict__ pool_w, const float* __restrict__ b1,
                               float* __restrict__ pred, float* __restrict__ wei_out) {
  int bid = blockIdx.x;                 // it*168 + b*21 + c
  int it = bid / 168, r = bid % 168;
  int b = r / NCLS, c = r % NCLS;
  int t = threadIdx.x;
  float scale = expf(pool_w[it * NCLS + c]);
  const float* ip = inp + ((size_t)(b * NCLS + c)) * 1024;
  float v[4]; float mx = -1e30f;
  #pragma unroll
  for (int i = 0; i < 4; ++i) { v[i] = ip[t + i * 256] * scale; mx = fmaxf(mx, v[i]); }
  __shared__ float red[4];
  #pragma unroll
  for (int off = 1; off < 64; off <<= 1) mx = fmaxf(mx, __shfl_xor(mx, off));
  if ((t & 63) == 0) red[t >> 6] = mx;
  __syncthreads();
  mx = fmaxf(fmaxf(red[0], red[1]), fmaxf(red[2], red[3]));
  __syncthreads();
  float s = 0.f;
  #pragma unroll
  for (int i = 0; i < 4; ++i) { v[i] = expf(v[i] - mx); s += v[i]; }
  #pragma unroll
  for (int off = 1; off < 64; off <<= 1) s += __shfl_xor(s, off);
  if ((t & 63) == 0) red[t >> 6] = s;
  __syncthreads();
  s = red[0] + red[1] + red[2] + red[3];
  float inv = 1.f / s;
  __syncthreads();
  const float* pj = proj + (((size_t)(it * BS + b)) * NCLS + c) * 1024;
  float ps = 0.f;
  #pragma unroll
  for (int i = 0; i < 4; ++i) {
    float wv = v[i] * inv;
    ps += wv * pj[t + i * 256];
    if (it == NIT - 1) wei_out[((size_t)(b * NCLS + c)) * 1024 + t + i * 256] = wv;
  }
  #pragma unroll
  for (int off = 1; off < 64; off <<= 1) ps += __shfl_xor(ps, off);
  if ((t & 63) == 0) red[t >> 6] = ps;
  __syncthreads();
  if (t == 0) pred[bid] = red[0] + red[1] + red[2] + red[3] + b1[it * NCLS + c];
}

// ---------------- prob = sigmoid(mean_it pred)
__global__ void prob_kernel(const float* __restrict__ pred, float* __restrict__ out) {
  int i = threadIdx.x;
  if (i < BS * NCLS) {
    float s = 0.f;
    #pragma unroll
    for (int it = 0; it < NIT; ++it) s += pred[it * BS * NCLS + i];
    s *= 0.25f;
    out[i] = 1.f / (1.f + expf(-s));
  }
}

extern "C" void kernel_launch(void* const* d_in, const int* in_sizes, int n_in,
                              void* d_out, int out_size, void* d_ws, size_t ws_size,
                              hipStream_t stream) {
  const float* x        = (const float*)d_in[0];
  const float* diffW    = (const float*)d_in[1];
  const float* conv2d_w = (const float*)d_in[2];
  const float* conv2d_b = (const float*)d_in[3];
  const float* conv1_w  = (const float*)d_in[4];
  const float* conv1_b  = (const float*)d_in[5];
  const float* pool_w   = (const float*)d_in[6];
  float* out = (float*)d_out;

  char* ws = (char*)d_ws;
  u16*   wt      = (u16*)(ws);                      // 150,994,944 B
  u16*   xT      = (u16*)(ws + 150994944);          //  33,554,432
  u16*   normT   = (u16*)(ws + 184549376);          //  16,777,216
  u16*   out_all = (u16*)(ws + 201326592);          //  67,108,864
  float* P       = (float*)(ws + 268435456);        //  11,010,048
  float* inp     = (float*)(ws + 279445504);        //     688,128
  float* pred    = (float*)(ws + 280133632);        //       2,688
  float* zpage   = (float*)(ws + 280136320);        //         256

  float* out_prob = out;                 // 168
  float* out_wc   = out + 168;           // 172032
  float* out_wei  = out + 168 + 172032;  // 172032

  hipLaunchKernelGGL(zero_kernel, dim3(1), dim3(64), 0, stream, zpage);
  hipLaunchKernelGGL(prep_w_kernel, dim3(4096), dim3(256), 0, stream, conv2d_w, wt);
  hipLaunchKernelGGL(prep_x_kernel, dim3(4096), dim3(256), 0, stream, x, xT);
  hipLaunchKernelGGL(norm_kernel, dim3(8192), dim3(256), 0, stream, diffW, normT);
  hipLaunchKernelGGL(conv8_kernel, dim3(512), dim3(512), 0, stream,
                     wt, xT, conv2d_b, (const u16*)zpage, out_all);
  hipLaunchKernelGGL(p_kernel, dim3(128), dim3(1024), 0, stream, out_all, conv1_w, P);
  hipLaunchKernelGGL(weicum2_kernel, dim3(32), dim3(256), 0, stream,
                     P, normT, conv1_b, out_wc, inp);
  hipLaunchKernelGGL(weipred_kernel, dim3(672), dim3(256), 0, stream,
                     inp, P, pool_w, conv1_b, pred, out_wei);
  hipLaunchKernelGGL(prob_kernel, dim3(1), dim3(256), 0, stream, pred, out_prob);
}

// Round 4
// 1197.698 us; speedup vs baseline: 2.1738x; 1.0598x over previous
//
#include <hip/hip_runtime.h>
#include <hip/hip_bf16.h>

typedef unsigned short u16;
typedef __attribute__((ext_vector_type(8))) short bf16x8;
typedef __attribute__((ext_vector_type(4))) float f32x4;

#define NIT 4
#define NCLS 21
#define BS 8
#define CIN 2048
#define COUT 1024
#define WH 1024

__device__ __forceinline__ u16 f2bf(float f) {
  union { float f; unsigned u; } v; v.f = f;
  unsigned r = v.u + 0x7fffu + ((v.u >> 16) & 1u);
  return (u16)(r >> 16);
}
__device__ __forceinline__ float bf2f(u16 h) {
  union { unsigned u; float f; } v; v.u = ((unsigned)h) << 16;
  return v.f;
}

#define GLDS16(gp, lp) __builtin_amdgcn_global_load_lds( \
    (const __attribute__((address_space(1))) unsigned int*)(gp), \
    (__attribute__((address_space(3))) unsigned int*)(lp), 16, 0, 0)

// ---------------- prep: conv2d_w [it][co][ci][3][3] f32 -> wt [it][tap][co][ci] bf16
__global__ void prep_w_kernel(const float* __restrict__ w, u16* __restrict__ wt) {
  int it = blockIdx.x >> 10, co = blockIdx.x & 1023;
  const float* src = w + (size_t)(it * 1024 + co) * (CIN * 9);
  __shared__ float ls[2304];
  int t = threadIdx.x;
  for (int chunk = 0; chunk < 8; ++chunk) {
    for (int i = t; i < 2304; i += 256) ls[i] = src[chunk * 2304 + i];
    __syncthreads();
    #pragma unroll
    for (int tap = 0; tap < 9; ++tap) {
      float v = ls[t * 9 + tap];
      wt[(((size_t)(it * 9 + tap) * 1024 + co) * CIN) + chunk * 256 + t] = f2bf(v);
    }
    __syncthreads();
  }
}

// ---------------- prep: x [b][ci][p] f32 -> xT [b][p][ci] bf16 (tiled transpose)
__global__ void prep_x_kernel(const float* __restrict__ x, u16* __restrict__ xT) {
  int bid = blockIdx.x;
  int pT = bid & 15, ciT = (bid >> 4) & 31, b = bid >> 9;
  __shared__ float ls[64][65];
  int t = threadIdx.x;
  int tr = t >> 6, tc = t & 63;
  const float* xp = x + ((size_t)b * CIN + ciT * 64) * WH + pT * 64;
  #pragma unroll
  for (int r = 0; r < 16; ++r) {
    int ci = r * 4 + tr;
    ls[ci][tc] = xp[(size_t)ci * WH + tc];
  }
  __syncthreads();
  u16* xtp = xT + ((size_t)b * WH + pT * 64) * CIN + ciT * 64;
  #pragma unroll
  for (int r = 0; r < 16; ++r) {
    int p = r * 4 + tr;
    xtp[(size_t)p * CIN + tc] = f2bf(ls[tc][p]);
  }
}

// ---------------- norm: diffW [b][m][n] -> normT[m][n] bf16 (threshold + row-normalize)
__global__ void norm_kernel(const float* __restrict__ diffW, u16* __restrict__ normT) {
  int b = blockIdx.x >> 10, m = blockIdx.x & 1023;
  const float* row = diffW + ((size_t)(b * 1024 + m)) * 1024;
  int t = threadIdx.x;
  float v[4]; float s = 0.f;
  #pragma unroll
  for (int i = 0; i < 4; ++i) {
    float x = row[t + i * 256];
    x = (x > 0.8f) ? x : 0.f;
    v[i] = x; s += x;
  }
  #pragma unroll
  for (int off = 1; off < 64; off <<= 1) s += __shfl_xor(s, off);
  __shared__ float red[4];
  if ((t & 63) == 0) red[t >> 6] = s;
  __syncthreads();
  float inv = 1.f / (red[0] + red[1] + red[2] + red[3]);
  u16* orow = normT + ((size_t)(b * 1024 + m)) * 1024;
  #pragma unroll
  for (int i = 0; i < 4; ++i) orow[t + i * 256] = f2bf(v[i] * inv);
}

__global__ void zero_kernel(float* p) { p[threadIdx.x] = 0.f; }

// ================ conv implicit GEMM, 256^2 tile, 8-phase (T2+T3+T4+T5)
// + T1 XCD mapping (b = bid&7 -> XCD), LPT heavy-first sequence, tap-range skip
// C[co][n] = sum_{tap,ci} wt[it][tap][co][ci] * xT[b][n'][ci]
__global__ __launch_bounds__(512, 2)
void conv8_kernel(const u16* __restrict__ wt, const u16* __restrict__ xT,
                  const float* __restrict__ bias, const u16* __restrict__ zpage,
                  u16* __restrict__ out_all) {
  const int bid = blockIdx.x;
  // XCD-aware decode: b on XCD (bid&7), seq heavy-first within XCD.
  const int b = bid & 7;
  const int s = bid >> 3;              // 0..63 temporal order per XCD
  const int g = s >> 2, mt = s & 3;
  const int it = g >> 2;
  const int nt = (int)((0x2130321030213210ULL >> (g * 4)) & 0xFULL);
  const int M0 = mt * 256, N0 = nt * 256;
  const int tid = threadIdx.x, wave = tid >> 6, lane = tid & 63;
  const int wm = wave >> 2, wn = wave & 3;         // 2 x 4 wave grid

  const int dil = 6 * (it + 1);
  // contiguous active-tap range: taps 0-2 (dy=-dil) dead iff 8nt+7<dil;
  // taps 6-8 (dy=+dil) dead iff 8nt+dil>=32
  const int tlo = (8 * nt + 7 < dil) ? 3 : 0;
  const int thi = (8 * nt + dil >= 32) ? 6 : 9;
  const int NT = (thi - tlo) * 32;                 // K-tiles of 64 (96/192/288)

  __shared__ u16 lds[2][2][256][64];               // [buf][A/B][row][col] = 128 KiB

  const u16* Aglob = wt + (size_t)it * 9 * COUT * CIN;
  const u16* Bglob = xT + (size_t)b * WH * CIN;

  const int srow = lane >> 3;                  // row within 8-row group
  const int scol16 = (lane & 7) ^ srow;        // inverse-swizzled source col16 (rule #21)

  // precomputed per-lane row base pointers + validity mask (absolute tap ids)
  const u16* abase[4]; const u16* bbase[4];
  unsigned long long vmask = 0ull;
  #pragma unroll
  for (int r = 0; r < 4; ++r) {
    int arow = M0 + r * 64 + wave * 8 + srow;
    abase[r] = Aglob + (size_t)arow * CIN + scol16 * 8;
    int n = N0 + r * 64 + wave * 8 + srow;
    bbase[r] = Bglob + (size_t)n * CIN + scol16 * 8;
    int py0 = n >> 5, px0 = n & 31;
    #pragma unroll
    for (int tap = 0; tap < 9; ++tap) {
      int t3 = (tap * 11) >> 5;
      int py = py0 + (t3 - 1) * dil;
      int px = px0 + (tap - t3 * 3 - 1) * dil;
      if (((unsigned)py < 32u) && ((unsigned)px < 32u))
        vmask |= (1ull << (r * 9 + tap));
    }
  }
  const u16* zp = zpage + scol16 * 8;

  auto stageA = [&](int jj, int hf, int bb) {
    if (jj >= NT) return;
    int tap = tlo + (jj >> 5);
    size_t uoff = (size_t)tap * (COUT * CIN) + (size_t)((jj & 31) << 6);
    #pragma unroll
    for (int i = 0; i < 2; ++i) {
      int r = hf * 2 + i;
      GLDS16(abase[r] + uoff, &lds[bb][0][hf * 128 + i * 64 + wave * 8][0]);
    }
  };
  auto stageB = [&](int jj, int hf, int bb) {
    if (jj >= NT) return;
    int tap = tlo + (jj >> 5);
    int t3 = (tap * 11) >> 5;
    ptrdiff_t toff = (ptrdiff_t)(((t3 - 1) * 32 + (tap - t3 * 3 - 1)) * dil) * CIN
                   + (ptrdiff_t)((jj & 31) << 6);
    #pragma unroll
    for (int i = 0; i < 2; ++i) {
      int r = hf * 2 + i;
      bool valid = (vmask >> (r * 9 + tap)) & 1ull;
      const u16* src = valid ? (bbase[r] + toff) : zp;
      GLDS16(src, &lds[bb][1][hf * 128 + i * 64 + wave * 8][0]);
    }
  };

  f32x4 acc[8][4] = {};

  const int l15 = lane & 15;
  const int colx[2] = { (((lane >> 4) ^ (lane & 7)) * 16),
                        (((4 + (lane >> 4)) ^ (lane & 7)) * 16) };
  const int arow_byte = (wm * 128 + l15) * 128;
  const int brow_byte = (wn * 64 + l15) * 128;

  // prologue: kt0 fully + B(1) in flight
  stageA(0, 0, 0); stageA(0, 1, 0);
  stageB(0, 0, 0); stageB(0, 1, 0);
  stageB(1, 0, 1); stageB(1, 1, 1);
  asm volatile("s_waitcnt vmcnt(4)" ::: "memory");
  __builtin_amdgcn_s_barrier();
  __builtin_amdgcn_sched_barrier(0);

  bf16x8 bfrag[4][2];
  for (int j = 0; j < NT; ++j) {
    const int p = j & 1;
    const char* Ab = (const char*)&lds[p][0][0][0];
    const char* Bb = (const char*)&lds[p][1][0][0];
    #pragma unroll
    for (int q = 0; q < 4; ++q) {
      // --- ds-read register subtile
      if (q == 0) {
        #pragma unroll
        for (int nf = 0; nf < 4; ++nf) {
          bfrag[nf][0] = *(const bf16x8*)(Bb + brow_byte + nf * 2048 + colx[0]);
          bfrag[nf][1] = *(const bf16x8*)(Bb + brow_byte + nf * 2048 + colx[1]);
        }
      }
      bf16x8 af[2][2];
      #pragma unroll
      for (int m = 0; m < 2; ++m) {
        af[m][0] = *(const bf16x8*)(Ab + arow_byte + (q * 2 + m) * 2048 + colx[0]);
        af[m][1] = *(const bf16x8*)(Ab + arow_byte + (q * 2 + m) * 2048 + colx[1]);
      }
      // --- stage one half-tile (counted pipeline)
      if (q == 0) stageA(j + 1, 0, p ^ 1);
      else if (q == 1) stageA(j + 1, 1, p ^ 1);
      else if (q == 2) stageB(j + 2, 0, p);
      else stageB(j + 2, 1, p);

      __builtin_amdgcn_s_barrier();
      asm volatile("s_waitcnt lgkmcnt(0)" ::: "memory");
      __builtin_amdgcn_sched_barrier(0);
      __builtin_amdgcn_s_setprio(1);
      #pragma unroll
      for (int m = 0; m < 2; ++m)
        #pragma unroll
        for (int nf = 0; nf < 4; ++nf) {
          acc[q * 2 + m][nf] = __builtin_amdgcn_mfma_f32_16x16x32_bf16(af[m][0], bfrag[nf][0], acc[q * 2 + m][nf], 0, 0, 0);
          acc[q * 2 + m][nf] = __builtin_amdgcn_mfma_f32_16x16x32_bf16(af[m][1], bfrag[nf][1], acc[q * 2 + m][nf], 0, 0, 0);
        }
      __builtin_amdgcn_s_setprio(0);
      if (q == 3) {
        if (j < NT - 2) { asm volatile("s_waitcnt vmcnt(4)" ::: "memory"); }
        else           { asm volatile("s_waitcnt vmcnt(0)" ::: "memory"); }
      }
      __builtin_amdgcn_s_barrier();
      __builtin_amdgcn_sched_barrier(0);
    }
  }

  // epilogue
  u16* outp = out_all + (size_t)(it * BS + b) * COUT * WH;
  const float* bias_it = bias + it * COUT;
  #pragma unroll
  for (int mf = 0; mf < 8; ++mf)
    #pragma unroll
    for (int nf = 0; nf < 4; ++nf) {
      int col = N0 + wn * 64 + nf * 16 + l15;
      #pragma unroll
      for (int r = 0; r < 4; ++r) {
        int row = M0 + wm * 128 + mf * 16 + (lane >> 4) * 4 + r;
        outp[((size_t)row << 10) + col] = f2bf(acc[mf][nf][r] + bias_it[row]);
      }
    }
}

// ---------------- P[it,b,c,k] = sum_d w1[it,c,d] * out[it,b,d,k]   (f32 out)
__global__ __launch_bounds__(1024, 4)
void p_kernel(const u16* __restrict__ out_all, const float* __restrict__ w1,
              float* __restrict__ P) {
  int bidx = blockIdx.x;
  int kch = bidx & 3, sl = bidx >> 2;   // sl = it*8+b
  int it = sl >> 3;
  int t = threadIdx.x;
  int wave = t >> 6, lane = t & 63;
  int g = wave & 3;
  int k = kch * 256 + (wave >> 2) * 64 + lane;
  __shared__ float w1f[21][512];
  const u16* op = out_all + ((size_t)sl << 20) + k;
  const float* w1p = w1 + (size_t)it * NCLS * 1024;
  float acc[6] = {0.f, 0.f, 0.f, 0.f, 0.f, 0.f};
  const int cbase = g * 6;
  for (int h = 0; h < 2; ++h) {
    __syncthreads();
    for (int l = t; l < 21 * 128; l += 1024) {
      int c = l >> 7, qq = l & 127;
      *(f32x4*)&w1f[c][qq * 4] = *(const f32x4*)(w1p + (size_t)c * 1024 + h * 512 + qq * 4);
    }
    __syncthreads();
    const u16* oph = op + ((size_t)(h * 512) << 10);
    #pragma unroll 4
    for (int dq = 0; dq < 128; ++dq) {
      float vv[4];
      #pragma unroll
      for (int j = 0; j < 4; ++j) vv[j] = bf2f(oph[(size_t)(dq * 4 + j) << 10]);
      #pragma unroll
      for (int cj = 0; cj < 6; ++cj) {
        int c = cbase + cj; if (c > 20) c = 20;
        f32x4 w4 = *(const f32x4*)&w1f[c][dq * 4];
        acc[cj] = fmaf(w4[0], vv[0], acc[cj]);
        acc[cj] = fmaf(w4[1], vv[1], acc[cj]);
        acc[cj] = fmaf(w4[2], vv[2], acc[cj]);
        acc[cj] = fmaf(w4[3], vv[3], acc[cj]);
      }
    }
  }
  float* Pp = P + (((size_t)sl * NCLS) << 10) + k;
  #pragma unroll
  for (int cj = 0; cj < 6; ++cj) {
    int c = cbase + cj;
    if (c < NCLS) Pp[(size_t)c << 10] = acc[cj];
  }
}

// ---------------- weicum2: o2sum[c,m] = sum_k Psum[c,k]*normT[m,k]; wc=softmax_c; inp=softmax_c(wc)
__global__ __launch_bounds__(256, 2)
void weicum2_kernel(const float* __restrict__ P, const u16* __restrict__ normT,
                    const float* __restrict__ b1, float* __restrict__ wc_out,
                    float* __restrict__ inp) {
  int bidx = blockIdx.x;  // 32 = b(8)*mch(4)
  int mch = bidx & 3, b = bidx >> 2;
  int t = threadIdx.x;
  __shared__ u16 ps[21][1024];   // Psum as bf16
  for (int l = t; l < 21 * 128; l += 256) {
    int c = l >> 7, qq = l & 127;
    float s[8] = {};
    #pragma unroll
    for (int itp = 0; itp < 4; ++itp) {
      const float* pp = P + ((((size_t)(itp * 8 + b)) * NCLS + c) << 10) + qq * 8;
      f32x4 a0 = *(const f32x4*)pp;
      f32x4 a1 = *(const f32x4*)(pp + 4);
      s[0] += a0[0]; s[1] += a0[1]; s[2] += a0[2]; s[3] += a0[3];
      s[4] += a1[0]; s[5] += a1[1]; s[6] += a1[2]; s[7] += a1[3];
    }
    bf16x8 pv;
    #pragma unroll
    for (int j = 0; j < 8; ++j) pv[j] = (short)f2bf(s[j]);
    *(bf16x8*)&ps[c][qq * 8] = pv;
  }
  __syncthreads();
  int m = mch * 256 + t;
  const u16* nr = normT + ((size_t)(b * 1024 + m)) * 1024;
  float acc[NCLS];
  #pragma unroll
  for (int c = 0; c < NCLS; ++c) acc[c] = 0.f;
  for (int oct = 0; oct < 128; ++oct) {
    bf16x8 nv = *(const bf16x8*)(nr + oct * 8);
    float nf[8];
    #pragma unroll
    for (int j = 0; j < 8; ++j) nf[j] = bf2f((u16)nv[j]);
    #pragma unroll
    for (int c = 0; c < NCLS; ++c) {
      bf16x8 pv = *(const bf16x8*)&ps[c][oct * 8];
      #pragma unroll
      for (int j = 0; j < 8; ++j) acc[c] = fmaf(nf[j], bf2f((u16)pv[j]), acc[c]);
    }
  }
  float mx = -1e30f;
  #pragma unroll
  for (int c = 0; c < NCLS; ++c) {
    float bs = 0.f;
    #pragma unroll
    for (int itp = 0; itp < NIT; ++itp) bs += b1[itp * NCLS + c];
    acc[c] = (acc[c] + bs) * 0.25f;
    mx = fmaxf(mx, acc[c]);
  }
  float s = 0.f;
  #pragma unroll
  for (int c = 0; c < NCLS; ++c) { acc[c] = expf(acc[c] - mx); s += acc[c]; }
  float inv = 1.f / s;
  float* wp = wc_out + (((size_t)b * NCLS) << 10) + m;
  float mx2 = -1e30f;
  #pragma unroll
  for (int c = 0; c < NCLS; ++c) {
    acc[c] *= inv;
    wp[(size_t)c << 10] = acc[c];
    mx2 = fmaxf(mx2, acc[c]);
  }
  float s2 = 0.f;
  #pragma unroll
  for (int c = 0; c < NCLS; ++c) { acc[c] = expf(acc[c] - mx2); s2 += acc[c]; }
  float inv2 = 1.f / s2;
  float* ip = inp + (((size_t)b * NCLS) << 10) + m;
  #pragma unroll
  for (int c = 0; c < NCLS; ++c) ip[(size_t)c << 10] = acc[c] * inv2;
}

// ---------------- per-(it,b,c): wei = softmax_n(inp*exp(pw)); pred = sum_n wei*P + b1
__global__ void weipred_kernel(const float* __restrict__ inp, const float* __restrict__ proj,
                               const float* __restrict__ pool_w, const float* __restrict__ b1,
                               float* __restrict__ pred, float* __restrict__ wei_out) {
  int bid = blockIdx.x;                 // it*168 + b*21 + c
  int it = bid / 168, r = bid % 168;
  int b = r / NCLS, c = r % NCLS;
  int t = threadIdx.x;
  float scale = expf(pool_w[it * NCLS + c]);
  const float* ip = inp + ((size_t)(b * NCLS + c)) * 1024;
  float v[4]; float mx = -1e30f;
  #pragma unroll
  for (int i = 0; i < 4; ++i) { v[i] = ip[t + i * 256] * scale; mx = fmaxf(mx, v[i]); }
  __shared__ float red[4];
  #pragma unroll
  for (int off = 1; off < 64; off <<= 1) mx = fmaxf(mx, __shfl_xor(mx, off));
  if ((t & 63) == 0) red[t >> 6] = mx;
  __syncthreads();
  mx = fmaxf(fmaxf(red[0], red[1]), fmaxf(red[2], red[3]));
  __syncthreads();
  float s = 0.f;
  #pragma unroll
  for (int i = 0; i < 4; ++i) { v[i] = expf(v[i] - mx); s += v[i]; }
  #pragma unroll
  for (int off = 1; off < 64; off <<= 1) s += __shfl_xor(s, off);
  if ((t & 63) == 0) red[t >> 6] = s;
  __syncthreads();
  s = red[0] + red[1] + red[2] + red[3];
  float inv = 1.f / s;
  __syncthreads();
  const float* pj = proj + (((size_t)(it * BS + b)) * NCLS + c) * 1024;
  float ps = 0.f;
  #pragma unroll
  for (int i = 0; i < 4; ++i) {
    float wv = v[i] * inv;
    ps += wv * pj[t + i * 256];
    if (it == NIT - 1) wei_out[((size_t)(b * NCLS + c)) * 1024 + t + i * 256] = wv;
  }
  #pragma unroll
  for (int off = 1; off < 64; off <<= 1) ps += __shfl_xor(ps, off);
  if ((t & 63) == 0) red[t >> 6] = ps;
  __syncthreads();
  if (t == 0) pred[bid] = red[0] + red[1] + red[2] + red[3] + b1[it * NCLS + c];
}

// ---------------- prob = sigmoid(mean_it pred)
__global__ void prob_kernel(const float* __restrict__ pred, float* __restrict__ out) {
  int i = threadIdx.x;
  if (i < BS * NCLS) {
    float s = 0.f;
    #pragma unroll
    for (int it = 0; it < NIT; ++it) s += pred[it * BS * NCLS + i];
    s *= 0.25f;
    out[i] = 1.f / (1.f + expf(-s));
  }
}

extern "C" void kernel_launch(void* const* d_in, const int* in_sizes, int n_in,
                              void* d_out, int out_size, void* d_ws, size_t ws_size,
                              hipStream_t stream) {
  const float* x        = (const float*)d_in[0];
  const float* diffW    = (const float*)d_in[1];
  const float* conv2d_w = (const float*)d_in[2];
  const float* conv2d_b = (const float*)d_in[3];
  const float* conv1_w  = (const float*)d_in[4];
  const float* conv1_b  = (const float*)d_in[5];
  const float* pool_w   = (const float*)d_in[6];
  float* out = (float*)d_out;

  char* ws = (char*)d_ws;
  u16*   wt      = (u16*)(ws);                      // 150,994,944 B
  u16*   xT      = (u16*)(ws + 150994944);          //  33,554,432
  u16*   normT   = (u16*)(ws + 184549376);          //  16,777,216
  u16*   out_all = (u16*)(ws + 201326592);          //  67,108,864
  float* P       = (float*)(ws + 268435456);        //  11,010,048
  float* inp     = (float*)(ws + 279445504);        //     688,128
  float* pred    = (float*)(ws + 280133632);        //       2,688
  float* zpage   = (float*)(ws + 280136320);        //         256

  float* out_prob = out;                 // 168
  float* out_wc   = out + 168;           // 172032
  float* out_wei  = out + 168 + 172032;  // 172032

  hipLaunchKernelGGL(zero_kernel, dim3(1), dim3(64), 0, stream, zpage);
  hipLaunchKernelGGL(prep_w_kernel, dim3(4096), dim3(256), 0, stream, conv2d_w, wt);
  hipLaunchKernelGGL(prep_x_kernel, dim3(4096), dim3(256), 0, stream, x, xT);
  hipLaunchKernelGGL(norm_kernel, dim3(8192), dim3(256), 0, stream, diffW, normT);
  hipLaunchKernelGGL(conv8_kernel, dim3(512), dim3(512), 0, stream,
                     wt, xT, conv2d_b, (const u16*)zpage, out_all);
  hipLaunchKernelGGL(p_kernel, dim3(128), dim3(1024), 0, stream, out_all, conv1_w, P);
  hipLaunchKernelGGL(weicum2_kernel, dim3(32), dim3(256), 0, stream,
                     P, normT, conv1_b, out_wc, inp);
  hipLaunchKernelGGL(weipred_kernel, dim3(672), dim3(256), 0, stream,
                     inp, P, pool_w, conv1_b, pred, out_wei);
  hipLaunchKernelGGL(prob_kernel, dim3(1), dim3(256), 0, stream, pred, out_prob);
}